// Round 12
// baseline (162.862 us; speedup 1.0000x reference)
//
#include <hip/hip_runtime.h>
#include <math.h>

// ---------------------------------------------------------------------------
// B=1024, conv1d(3->64,k=5,pad=2) T=100, LSTM(64->128) 100 steps (MFMA f16),
// per-row epilogue (W1c tanh, W2, W0, LN, linear), tile to (14,14).
//
// LSTM: 64 blocks x 512 thr (8 waves, 2/SIMD). Block owns 16 batch rows.
// r12 = r11 + x OFF the LDS/barrier path: x A-fragments are loaded straight
// from global into registers (2x16B/thread, issued 2 steps ahead -> L2
// latency hidden), x-MFMAs issue before the h ds_reads and overlap their
// latency. LDS is h-only (8KB, double-buffered, swizzled). r11 step budget:
// 2207cyc = 931 MFMA-issue + ~220 VALU + ~150 LDS + ~900 stall on the
// barrier->ds_read->MFMA-chain->pointwise serial path; this fills the
// ds_read shadow and deletes the x staging work.
// ---------------------------------------------------------------------------

#define T_STEPS 100

// workspace byte offsets
#define OFF_WHI    0u          // 98304 f16 folded weights
#define OFF_BIAS   393216u     // 512 f32 folded bias
#define OFF_W1CT   395264u     // 16384 f32
#define OFF_W2T    460800u
#define OFF_W0T    526336u
#define OFF_LINWT  591872u
#define OFF_XHI    657408u     // 100*1024*64 f16
#define OFF_HFIN   26871808u   // 1024*128 f32

typedef __attribute__((ext_vector_type(8))) _Float16 half8;
typedef __attribute__((ext_vector_type(4))) float f32x4;

__device__ __forceinline__ float frcp(float x) { return __builtin_amdgcn_rcpf(x); }
__device__ __forceinline__ float fexp2(float x) { return __builtin_amdgcn_exp2f(x); }
__device__ __forceinline__ float tanhf_fast(float x) { return 2.f * frcp(1.f + __expf(-2.f * x)) - 1.f; }

#define MF16(A, B, C) __builtin_amdgcn_mfma_f32_16x16x32_f16((A), (B), (C), 0, 0, 0)

// ---------------------------------------------------------------------------
// prep_conv: blk<321 = weight packing (folded) + epilogue transposes;
//            blk>=321 = conv for batch row (blk-321).   (identical to r11)
// ---------------------------------------------------------------------------
__global__ __launch_bounds__(512)
void prep_conv_kernel(const float* __restrict__ w_ih, const float* __restrict__ w_hh,
                      const float* __restrict__ b_ih, const float* __restrict__ b_hh,
                      const float* __restrict__ W1, const float* __restrict__ W2,
                      const float* __restrict__ W0, const float* __restrict__ lin_w,
                      const float* __restrict__ x, const float* __restrict__ conv_w,
                      const float* __restrict__ conv_b, char* __restrict__ wsb) {
    __shared__ float sx[3][104];
    __shared__ float sw[960];
    __shared__ float sb[64];

    _Float16* whi  = (_Float16*)(wsb + OFF_WHI);
    float*  biasv = (float*)(wsb + OFF_BIAS);
    float*  W1cT  = (float*)(wsb + OFF_W1CT);
    float*  W2T   = (float*)(wsb + OFF_W2T);
    float*  W0T   = (float*)(wsb + OFF_W0T);
    float*  linWT = (float*)(wsb + OFF_LINWT);
    _Float16* xhi = (_Float16*)(wsb + OFF_XHI);

    const float fold[4] = {-1.4426950408889634f, -1.4426950408889634f,
                           -2.8853900817779268f, -1.4426950408889634f};

    int blk = blockIdx.x, tid = threadIdx.x;
    if (blk < 192) {
        int idx = blk * 512 + tid;
        int e = idx & 7;
        int l = (idx >> 3) & 63;
        int s = (idx >> 9) & 3;
        int rem = idx >> 11;           // w*6 + kt
        int kt = rem % 6, w = rem / 6;
        int g = s * 128 + 16 * w + (l & 15);
        int k = kt * 32 + (l >> 4) * 8 + e;
        float v = (k < 64) ? w_ih[g * 64 + k] : w_hh[g * 128 + (k - 64)];
        whi[idx] = (_Float16)(v * fold[s]);
    } else if (blk == 192) {
        int s = tid >> 7;
        biasv[tid] = (b_ih[tid] + b_hh[tid]) * fold[s];
    } else if (blk < 225) {
        int idx = (blk - 193) * 512 + tid;
        int f = idx >> 7, hh = idx & 127;
        W1cT[f * 128 + hh] = W1[hh * 256 + f] + W1[hh * 256 + 128 + f];
    } else if (blk < 257) {
        int idx = (blk - 225) * 512 + tid;
        int h = idx >> 7, f = idx & 127;
        W2T[h * 128 + f] = W2[f * 128 + h];
    } else if (blk < 289) {
        int idx = (blk - 257) * 512 + tid;
        int k = idx >> 7, f = idx & 127;
        W0T[k * 128 + f] = W0[f * 128 + k];
    } else if (blk < 321) {
        int idx = (blk - 289) * 512 + tid;
        int k = idx >> 7, f = idx & 127;
        linWT[k * 128 + f] = lin_w[f * 128 + k];
    } else {
        int b = blk - 321;
        for (int i = tid; i < 312; i += 512) {
            int c = i / 104, tp = i % 104;
            int t = tp - 2;
            sx[c][tp] = (t >= 0 && t < 100) ? x[b * 38400 + c * 100 + t] : 0.f;
        }
        for (int i = tid; i < 960; i += 512) sw[i] = conv_w[i];
        if (tid < 64) sb[tid] = conv_b[tid];
        __syncthreads();

        for (int i = tid; i < 6400; i += 512) {
            int t = i >> 6, k = i & 63;
            float a = sb[k];
#pragma unroll
            for (int c = 0; c < 3; ++c)
#pragma unroll
                for (int kk = 0; kk < 5; ++kk)
                    a += sx[c][t + kk] * sw[k * 15 + c * 5 + kk];
            a = fmaxf(a, 0.f);
            xhi[t * 65536 + b * 64 + k] = (_Float16)a;
        }
    }
}

// ---------------------------------------------------------------------------
// lstm_mfma: 64 blocks x 512 threads; x from global->regs, h-only LDS (8KB).
// ---------------------------------------------------------------------------
__global__ __launch_bounds__(512, 2)
void lstm_mfma(const char* __restrict__ wsro, char* __restrict__ wsb) {
    const _Float16* whi  = (const _Float16*)(wsro + OFF_WHI);
    const float*  biasv  = (const float*)(wsro + OFF_BIAS);
    const _Float16* xhi  = (const _Float16*)(wsro + OFF_XHI);
    float* hfin = (float*)(wsb + OFF_HFIN);

    __shared__ _Float16 H[2][16][128];   // h double-buffer, 8 KB, swizzled

    int tid = threadIdx.x;
    int w = tid >> 6, l = tid & 63;
    int b0 = blockIdx.x * 16;

    // ---- folded weights pinned in regs/AGPRs: x-part 8 frags, h-part 16
    half8 wx[2][4];                   // kt 0..1 (K 0..63)
    half8 wh[4][4];                   // kt 2..5 (K 64..191)
#pragma unroll
    for (int ktx = 0; ktx < 2; ++ktx)
#pragma unroll
        for (int s = 0; s < 4; ++s)
            wx[ktx][s] = *(const half8*)(whi + (((w * 6 + ktx) * 4 + s) * 64 + l) * 8);
#pragma unroll
    for (int kth = 0; kth < 4; ++kth)
#pragma unroll
        for (int s = 0; s < 4; ++s)
            wh[kth][s] = *(const half8*)(whi + (((w * 6 + 2 + kth) * 4 + s) * 64 + l) * 8);

    int jl = 16 * w + (l & 15);
    f32x4 bvec[4];
#pragma unroll
    for (int s = 0; s < 4; ++s) {
        float bv = biasv[s * 128 + jl];
        bvec[s] = (f32x4){bv, bv, bv, bv};
    }

    int arow = l & 15;
    uint g16b = (uint)(l >> 4) << 4;          // byte offset of 8-elem k-slice
    uint rswz = (uint)(arow & 7) << 4;
    int hrow0 = (l >> 4) * 4;

    char* hb = (char*)&H[0][0][0];

    // h read addresses (bytes within a 4096B plane), kth = 0..3
    const uint ha0 = ((uint)arow * 256u + 0u   + g16b) ^ rswz;
    const uint ha1 = ((uint)arow * 256u + 64u  + g16b) ^ rswz;
    const uint ha2 = ((uint)arow * 256u + 128u + g16b) ^ rswz;
    const uint ha3 = ((uint)arow * 256u + 192u + g16b) ^ rswz;
    // h write addresses for r=0..3
    uint hw_[4];
#pragma unroll
    for (int r = 0; r < 4; ++r) {
        uint row = (uint)(hrow0 + r);
        hw_[r] = (row * 256u + 2u * (uint)jl) ^ ((row & 7u) << 4);
    }

    // x A-fragment global base: row b0+arow, k-slice (l>>4)*8  (16B aligned)
    const _Float16* xb = xhi + (size_t)(b0 + arow) * 64 + (size_t)((l >> 4) * 8);

    float cst[4]  = {0.f, 0.f, 0.f, 0.f};
    float hreg[4] = {0.f, 0.f, 0.f, 0.f};

    // zero h planes (t=0 reads zeros)
    for (int i = tid; i < 2048; i += 512) ((uint*)hb)[i] = 0u;

    // prologue: x frags for t=0 (ga) and t=1 (gb)
    half8 ga0 = *(const half8*)(xb);
    half8 ga1 = *(const half8*)(xb + 32);
    half8 gb0 = *(const half8*)(xb + 65536);
    half8 gb1 = *(const half8*)(xb + 65536 + 32);
    __syncthreads();                       // zeros visible

#define PWISE(R)                                                              \
    { float Ei = fexp2(acc[0][R]);                                           \
      float Ef = fexp2(acc[1][R]);                                           \
      float Eg = fexp2(acc[2][R]);                                           \
      float Eo = fexp2(acc[3][R]);                                           \
      float rf  = frcp(1.f + Ef);                                            \
      float rig = frcp((1.f + Ei) * (1.f + Eg));                             \
      cst[R] = rf * cst[R] + (1.f - Eg) * rig;                                \
      float Ec = fexp2(cst[R] * -2.8853900817779268f);                        \
      float roc = frcp((1.f + Eo) * (1.f + Ec));                              \
      hreg[R] = (1.f - Ec) * roc; }

#define XSTEP(GX0, GX1, POFF, QOFF, TNEXT, DOWRITE)                           \
    { f32x4 acc[4];                                                           \
      _Pragma("unroll")                                                       \
      for (int s = 0; s < 4; ++s) acc[s] = MF16(GX0, wx[0][s], bvec[s]);      \
      _Pragma("unroll")                                                       \
      for (int s = 0; s < 4; ++s) acc[s] = MF16(GX1, wx[1][s], acc[s]);       \
      GX0 = *(const half8*)(xb + (size_t)(TNEXT) * 65536);                    \
      GX1 = *(const half8*)(xb + (size_t)(TNEXT) * 65536 + 32);               \
      const char* hp = hb + (POFF);                                           \
      half8 ah0 = *(const half8*)(hp + ha0);                                  \
      half8 ah1 = *(const half8*)(hp + ha1);                                  \
      half8 ah2 = *(const half8*)(hp + ha2);                                  \
      half8 ah3 = *(const half8*)(hp + ha3);                                  \
      _Pragma("unroll")                                                       \
      for (int s = 0; s < 4; ++s) acc[s] = MF16(ah0, wh[0][s], acc[s]);       \
      _Pragma("unroll")                                                       \
      for (int s = 0; s < 4; ++s) acc[s] = MF16(ah1, wh[1][s], acc[s]);       \
      _Pragma("unroll")                                                       \
      for (int s = 0; s < 4; ++s) acc[s] = MF16(ah2, wh[2][s], acc[s]);       \
      _Pragma("unroll")                                                       \
      for (int s = 0; s < 4; ++s) acc[s] = MF16(ah3, wh[3][s], acc[s]);       \
      PWISE(0) PWISE(1) PWISE(2) PWISE(3)                                     \
      if (DOWRITE) {                                                          \
          char* hq = hb + (QOFF);                                             \
          _Pragma("unroll")                                                   \
          for (int r = 0; r < 4; ++r)                                         \
              *(_Float16*)(hq + hw_[r]) = (_Float16)hreg[r];                  \
          __syncthreads();                                                    \
      } }

    for (int tt = 0; tt < T_STEPS; tt += 2) {
        int tn0 = (tt + 2 < T_STEPS) ? tt + 2 : T_STEPS - 1;
        XSTEP(ga0, ga1, 0, 4096, tn0, true)            // even t: read P0, write P1
        int tn1 = (tt + 3 < T_STEPS) ? tt + 3 : T_STEPS - 1;
        XSTEP(gb0, gb1, 4096, 0, tn1, (tt < T_STEPS - 2)) // odd t: read P1, write P0
    }
#undef XSTEP
#undef PWISE

#pragma unroll
    for (int r = 0; r < 4; ++r)
        hfin[(size_t)(b0 + hrow0 + r) * 128 + jl] = hreg[r];
}

// ---------------------------------------------------------------------------
// post: per row: u=tanh(W1c@h); v=W2@u; res=W0@h+127v; LN; linear; tile 196x
// with float4 stores.   (identical to r11)
// ---------------------------------------------------------------------------
__global__ __launch_bounds__(128) void post_kernel(const char* __restrict__ wsb,
                                                   const float* __restrict__ ln_g,
                                                   const float* __restrict__ ln_b,
                                                   const float* __restrict__ lin_b,
                                                   float* __restrict__ out) {
    const float* hfinal = (const float*)(wsb + OFF_HFIN);
    const float* W1cT   = (const float*)(wsb + OFF_W1CT);
    const float* W2T    = (const float*)(wsb + OFF_W2T);
    const float* W0T    = (const float*)(wsb + OFF_W0T);
    const float* linWT  = (const float*)(wsb + OFF_LINWT);

    __shared__ float sh[128], su[128], sres[128], so_[128], spart[4];
    int b = blockIdx.x, f = threadIdx.x;

    sh[f] = hfinal[(size_t)b * 128 + f];
    __syncthreads();

    float acc = 0.f;
#pragma unroll 4
    for (int k = 0; k < 128; ++k) acc += W1cT[k * 128 + f] * sh[k];
    su[f] = tanhf_fast(acc);
    __syncthreads();

    float v = 0.f, r0 = 0.f;
#pragma unroll 4
    for (int k = 0; k < 128; ++k) {
        v  += W2T[k * 128 + f] * su[k];
        r0 += W0T[k * 128 + f] * sh[k];
    }
    float res = r0 + 127.f * v;

    int lane = f & 63, wid = f >> 6;
    float s = res;
#pragma unroll
    for (int off = 32; off > 0; off >>= 1) s += __shfl_down(s, off);
    if (lane == 0) spart[wid] = s;
    __syncthreads();
    float mu = (spart[0] + spart[1]) * (1.f / 128.f);
    float d = res - mu;
    float s2 = d * d;
#pragma unroll
    for (int off = 32; off > 0; off >>= 1) s2 += __shfl_down(s2, off);
    if (lane == 0) spart[2 + wid] = s2;
    __syncthreads();
    float var = (spart[2] + spart[3]) * (1.f / 128.f);
    float rn = d * rsqrtf(var + 1e-5f) * ln_g[f] + ln_b[f];
    sres[f] = rn;
    __syncthreads();

    float o = lin_b[f];
#pragma unroll 4
    for (int k = 0; k < 128; ++k) o += linWT[k * 128 + f] * sres[k];
    so_[f] = o;
    __syncthreads();

    float4 val = *(const float4*)&so_[(f & 31) << 2];
    float4* op4 = (float4*)(out + (size_t)b * 25088);
#pragma unroll 7
    for (int i = 0; i < 49; ++i) op4[i * 128 + f] = val;
}

// ---------------------------------------------------------------------------
extern "C" void kernel_launch(void* const* d_in, const int* in_sizes, int n_in,
                              void* d_out, int out_size, void* d_ws, size_t ws_size,
                              hipStream_t stream) {
    const float* x      = (const float*)d_in[0];
    const float* conv_w = (const float*)d_in[1];
    const float* conv_b = (const float*)d_in[2];
    const float* w_ih   = (const float*)d_in[3];
    const float* w_hh   = (const float*)d_in[4];
    const float* b_ih   = (const float*)d_in[5];
    const float* b_hh   = (const float*)d_in[6];
    const float* W1     = (const float*)d_in[7];
    const float* W2     = (const float*)d_in[8];
    const float* W0     = (const float*)d_in[9];
    const float* ln_g   = (const float*)d_in[10];
    const float* ln_b   = (const float*)d_in[11];
    const float* lin_w  = (const float*)d_in[12];
    const float* lin_b  = (const float*)d_in[13];
    char* wsb  = (char*)d_ws;
    float* out = (float*)d_out;

    prep_conv_kernel<<<dim3(1345), dim3(512), 0, stream>>>(w_ih, w_hh, b_ih, b_hh,
                                                           W1, W2, W0, lin_w,
                                                           x, conv_w, conv_b, wsb);
    lstm_mfma<<<dim3(64), dim3(512), 0, stream>>>(wsb, wsb);
    post_kernel<<<dim3(1024), dim3(128), 0, stream>>>(wsb, ln_g, ln_b, lin_b, out);
}

// Round 13
// 148.254 us; speedup vs baseline: 1.0985x; 1.0985x over previous
//
#include <hip/hip_runtime.h>
#include <math.h>

// ---------------------------------------------------------------------------
// B=1024, conv1d(3->64,k=5,pad=2) T=100, LSTM(64->128) 100 steps (MFMA f16),
// per-row epilogue (W1c tanh, W2, W0, LN, linear), tile to (14,14).
//
// LSTM: 64 blocks x 512 thr (8 waves, 2/SIMD). Block owns 16 batch rows.
// r13 = r11 (known-good 148.4us; r12's global-x regressed and was reverted)
// + latency micro-reorders in the step body ONLY:
//   (1) A-frag ds_reads issued FIRST after the barrier (before x ds_write +
//       global prefetch) so MFMAs start as early as possible.
//   (2) PWISE interleaved with its h ds_write (earlier barrier arrival).
//   (3) last iteration peeled (no uniform branch in the hot loop).
// Step budget (r11): 2207cyc = 931 MFMA-issue + ~480 VALU/trans + ~900
// serial-chain stall; structural escapes all falsified (r6 spill, r12
// global-x, 32-block MFMA floor 77.6us). This shaves the chain head/tail.
// ---------------------------------------------------------------------------

#define T_STEPS 100
#define LROW    208          // f16 elems per LDS row (416 B, 16B-aligned)
#define PLANE   (16 * LROW)  // f16 elems per [16][LROW] plane

// workspace byte offsets
#define OFF_WHI    0u          // 98304 f16 folded weights
#define OFF_BIAS   393216u     // 512 f32 folded bias
#define OFF_W1CT   395264u     // 16384 f32
#define OFF_W2T    460800u
#define OFF_W0T    526336u
#define OFF_LINWT  591872u
#define OFF_XHI    657408u     // 100*1024*64 f16
#define OFF_HFIN   26871808u   // 1024*128 f32

typedef __attribute__((ext_vector_type(8))) _Float16 half8;
typedef __attribute__((ext_vector_type(4))) float f32x4;

__device__ __forceinline__ float frcp(float x) { return __builtin_amdgcn_rcpf(x); }
__device__ __forceinline__ float fexp2(float x) { return __builtin_amdgcn_exp2f(x); }
__device__ __forceinline__ float tanhf_fast(float x) { return 2.f * frcp(1.f + __expf(-2.f * x)) - 1.f; }

#define MF16(A, B, C) __builtin_amdgcn_mfma_f32_16x16x32_f16((A), (B), (C), 0, 0, 0)

// ---------------------------------------------------------------------------
// prep_conv: blk<321 = weight packing (folded) + epilogue transposes;
//            blk>=321 = conv for batch row (blk-321).   (identical to r11)
// ---------------------------------------------------------------------------
__global__ __launch_bounds__(512)
void prep_conv_kernel(const float* __restrict__ w_ih, const float* __restrict__ w_hh,
                      const float* __restrict__ b_ih, const float* __restrict__ b_hh,
                      const float* __restrict__ W1, const float* __restrict__ W2,
                      const float* __restrict__ W0, const float* __restrict__ lin_w,
                      const float* __restrict__ x, const float* __restrict__ conv_w,
                      const float* __restrict__ conv_b, char* __restrict__ wsb) {
    __shared__ float sx[3][104];
    __shared__ float sw[960];
    __shared__ float sb[64];

    _Float16* whi  = (_Float16*)(wsb + OFF_WHI);
    float*  biasv = (float*)(wsb + OFF_BIAS);
    float*  W1cT  = (float*)(wsb + OFF_W1CT);
    float*  W2T   = (float*)(wsb + OFF_W2T);
    float*  W0T   = (float*)(wsb + OFF_W0T);
    float*  linWT = (float*)(wsb + OFF_LINWT);
    _Float16* xhi = (_Float16*)(wsb + OFF_XHI);

    const float fold[4] = {-1.4426950408889634f, -1.4426950408889634f,
                           -2.8853900817779268f, -1.4426950408889634f};

    int blk = blockIdx.x, tid = threadIdx.x;
    if (blk < 192) {
        int idx = blk * 512 + tid;
        int e = idx & 7;
        int l = (idx >> 3) & 63;
        int s = (idx >> 9) & 3;
        int rem = idx >> 11;           // w*6 + kt
        int kt = rem % 6, w = rem / 6;
        int g = s * 128 + 16 * w + (l & 15);
        int k = kt * 32 + (l >> 4) * 8 + e;
        float v = (k < 64) ? w_ih[g * 64 + k] : w_hh[g * 128 + (k - 64)];
        whi[idx] = (_Float16)(v * fold[s]);
    } else if (blk == 192) {
        int s = tid >> 7;
        biasv[tid] = (b_ih[tid] + b_hh[tid]) * fold[s];
    } else if (blk < 225) {
        int idx = (blk - 193) * 512 + tid;
        int f = idx >> 7, hh = idx & 127;
        W1cT[f * 128 + hh] = W1[hh * 256 + f] + W1[hh * 256 + 128 + f];
    } else if (blk < 257) {
        int idx = (blk - 225) * 512 + tid;
        int h = idx >> 7, f = idx & 127;
        W2T[h * 128 + f] = W2[f * 128 + h];
    } else if (blk < 289) {
        int idx = (blk - 257) * 512 + tid;
        int k = idx >> 7, f = idx & 127;
        W0T[k * 128 + f] = W0[f * 128 + k];
    } else if (blk < 321) {
        int idx = (blk - 289) * 512 + tid;
        int k = idx >> 7, f = idx & 127;
        linWT[k * 128 + f] = lin_w[f * 128 + k];
    } else {
        int b = blk - 321;
        for (int i = tid; i < 312; i += 512) {
            int c = i / 104, tp = i % 104;
            int t = tp - 2;
            sx[c][tp] = (t >= 0 && t < 100) ? x[b * 38400 + c * 100 + t] : 0.f;
        }
        for (int i = tid; i < 960; i += 512) sw[i] = conv_w[i];
        if (tid < 64) sb[tid] = conv_b[tid];
        __syncthreads();

        for (int i = tid; i < 6400; i += 512) {
            int t = i >> 6, k = i & 63;
            float a = sb[k];
#pragma unroll
            for (int c = 0; c < 3; ++c)
#pragma unroll
                for (int kk = 0; kk < 5; ++kk)
                    a += sx[c][t + kk] * sw[k * 15 + c * 5 + kk];
            a = fmaxf(a, 0.f);
            xhi[t * 65536 + b * 64 + k] = (_Float16)a;
        }
    }
}

// ---------------------------------------------------------------------------
// lstm_mfma: 64 blocks x 512 threads, f16 datapath, 1 barrier/step.
// ---------------------------------------------------------------------------
__global__ __launch_bounds__(512, 2)
void lstm_mfma(const char* __restrict__ wsro, char* __restrict__ wsb) {
    const _Float16* whi  = (const _Float16*)(wsro + OFF_WHI);
    const float*  biasv  = (const float*)(wsro + OFF_BIAS);
    const _Float16* xhi  = (const _Float16*)(wsro + OFF_XHI);
    float* hfin = (float*)(wsb + OFF_HFIN);

    __shared__ _Float16 L[2][16][LROW];   // [buf][row][col] (x: 0..63, h: 64..191)

    int tid = threadIdx.x;
    int w = tid >> 6, l = tid & 63;
    int b0 = blockIdx.x * 16;

    // ---- folded weights pinned in regs/AGPRs: x-part 8 frags, h-part 16
    half8 wx[2][4];                   // kt 0..1 (K 0..63)
    half8 wh[4][4];                   // kt 2..5 (K 64..191)
#pragma unroll
    for (int ktx = 0; ktx < 2; ++ktx)
#pragma unroll
        for (int s = 0; s < 4; ++s)
            wx[ktx][s] = *(const half8*)(whi + (((w * 6 + ktx) * 4 + s) * 64 + l) * 8);
#pragma unroll
    for (int kth = 0; kth < 4; ++kth)
#pragma unroll
        for (int s = 0; s < 4; ++s)
            wh[kth][s] = *(const half8*)(whi + (((w * 6 + 2 + kth) * 4 + s) * 64 + l) * 8);

    int jl = 16 * w + (l & 15);
    f32x4 bvec[4];
#pragma unroll
    for (int s = 0; s < 4; ++s) {
        float bv = biasv[s * 128 + jl];
        bvec[s] = (f32x4){bv, bv, bv, bv};
    }

    int arow = l & 15;
    int g16  = (l >> 4) * 16;
    uint rowbase = (uint)arow * (LROW * 2);
    uint rswz    = (uint)(arow & 7) << 4;
    int hrow0 = (l >> 4) * 4;

    // x staging address (byte offset within a plane), swizzled
    int xr = tid >> 5;
    uint xw = ((uint)xr * (LROW * 2) + (uint)(tid & 31) * 4) ^ ((uint)(xr & 7) << 4);

    // h write offsets for r=0..3 (byte offsets)
    uint hwa[4];
#pragma unroll
    for (int r = 0; r < 4; ++r) {
        uint row = (uint)(hrow0 + r);
        hwa[r] = (row * (LROW * 2) + 128u + 2u * (uint)jl) ^ ((row & 7u) << 4);
    }

    float cst[4]  = {0.f, 0.f, 0.f, 0.f};
    float hreg[4] = {0.f, 0.f, 0.f, 0.f};

    // zero LDS (h regions must read 0 at t=0)
    for (int i = tid; i < 2 * PLANE; i += 512) ((_Float16*)L)[i] = (_Float16)0.f;

    // prologue: x(0) staged into buf0, vx holds x(1)
    size_t xoff0 = (size_t)b0 * 64 + (size_t)tid * 2;
    uint vx = *(const uint*)(xhi + xoff0);
    __syncthreads();                       // zeros visible
    *(uint*)((char*)&L[0][0][0] + xw) = vx;
    vx = *(const uint*)(xhi + xoff0 + 65536);
    __syncthreads();                       // x(0) visible

    // ---- main loop: steps 0..98 (write h + barrier); step 99 peeled.
    for (int t = 0; t < T_STEPS - 1; ++t) {
        int p = t & 1;
        const char* ph = (const char*)&L[p][0][0];
        char* qh = (char*)&L[p ^ 1][0][0];

        // (1) A-frag ds_reads FIRST (LDS pipe: reads ahead of writes)
        half8 ax0 = *(const half8*)(ph + ((rowbase + 0u   + g16) ^ rswz));
        half8 ax1 = *(const half8*)(ph + ((rowbase + 64u  + g16) ^ rswz));
        half8 ah0 = *(const half8*)(ph + ((rowbase + 128u + g16) ^ rswz));
        half8 ah1 = *(const half8*)(ph + ((rowbase + 192u + g16) ^ rswz));
        half8 ah2 = *(const half8*)(ph + ((rowbase + 256u + g16) ^ rswz));
        half8 ah3 = *(const half8*)(ph + ((rowbase + 320u + g16) ^ rswz));

        // (2) then stage x(t+1) from regs; issue prefetch x(t+2) (a full
        // step before the barrier's vmcnt drain).
        *(uint*)(qh + xw) = vx;
        int tn = (t + 2 < T_STEPS) ? t + 2 : T_STEPS - 1;
        vx = *(const uint*)(xhi + xoff0 + (size_t)tn * 65536);

        // (3) MFMA: single acc chain per gate, seeded by bias as C operand
        f32x4 acc[4];
#pragma unroll
        for (int s = 0; s < 4; ++s) acc[s] = MF16(ax0, wx[0][s], bvec[s]);
#pragma unroll
        for (int s = 0; s < 4; ++s) acc[s] = MF16(ax1, wx[1][s], acc[s]);
#pragma unroll
        for (int s = 0; s < 4; ++s) acc[s] = MF16(ah0, wh[0][s], acc[s]);
#pragma unroll
        for (int s = 0; s < 4; ++s) acc[s] = MF16(ah1, wh[1][s], acc[s]);
#pragma unroll
        for (int s = 0; s < 4; ++s) acc[s] = MF16(ah2, wh[2][s], acc[s]);
#pragma unroll
        for (int s = 0; s < 4; ++s) acc[s] = MF16(ah3, wh[3][s], acc[s]);

        // (4) pointwise (exp2-folded + rcp-merged), h-write interleaved per r
#pragma unroll
        for (int r = 0; r < 4; ++r) {
            float Ei = fexp2(acc[0][r]);
            float Ef = fexp2(acc[1][r]);
            float Eg = fexp2(acc[2][r]);
            float Eo = fexp2(acc[3][r]);
            float rf  = frcp(1.f + Ef);
            float rig = frcp((1.f + Ei) * (1.f + Eg));
            cst[r] = rf * cst[r] + (1.f - Eg) * rig;
            float Ec = fexp2(cst[r] * -2.8853900817779268f);
            float roc = frcp((1.f + Eo) * (1.f + Ec));
            hreg[r] = (1.f - Ec) * roc;
            *(_Float16*)(qh + hwa[r]) = (_Float16)hreg[r];   // write ASAP
        }

        __syncthreads();
    }

    // ---- peeled final step (t = 99): no staging, no h-write, no barrier
    {
        const char* ph = (const char*)&L[(T_STEPS - 1) & 1][0][0];
        half8 ax0 = *(const half8*)(ph + ((rowbase + 0u   + g16) ^ rswz));
        half8 ax1 = *(const half8*)(ph + ((rowbase + 64u  + g16) ^ rswz));
        half8 ah0 = *(const half8*)(ph + ((rowbase + 128u + g16) ^ rswz));
        half8 ah1 = *(const half8*)(ph + ((rowbase + 192u + g16) ^ rswz));
        half8 ah2 = *(const half8*)(ph + ((rowbase + 256u + g16) ^ rswz));
        half8 ah3 = *(const half8*)(ph + ((rowbase + 320u + g16) ^ rswz));

        f32x4 acc[4];
#pragma unroll
        for (int s = 0; s < 4; ++s) acc[s] = MF16(ax0, wx[0][s], bvec[s]);
#pragma unroll
        for (int s = 0; s < 4; ++s) acc[s] = MF16(ax1, wx[1][s], acc[s]);
#pragma unroll
        for (int s = 0; s < 4; ++s) acc[s] = MF16(ah0, wh[0][s], acc[s]);
#pragma unroll
        for (int s = 0; s < 4; ++s) acc[s] = MF16(ah1, wh[1][s], acc[s]);
#pragma unroll
        for (int s = 0; s < 4; ++s) acc[s] = MF16(ah2, wh[2][s], acc[s]);
#pragma unroll
        for (int s = 0; s < 4; ++s) acc[s] = MF16(ah3, wh[3][s], acc[s]);

#pragma unroll
        for (int r = 0; r < 4; ++r) {
            float Ei = fexp2(acc[0][r]);
            float Ef = fexp2(acc[1][r]);
            float Eg = fexp2(acc[2][r]);
            float Eo = fexp2(acc[3][r]);
            float rf  = frcp(1.f + Ef);
            float rig = frcp((1.f + Ei) * (1.f + Eg));
            cst[r] = rf * cst[r] + (1.f - Eg) * rig;
            float Ec = fexp2(cst[r] * -2.8853900817779268f);
            float roc = frcp((1.f + Eo) * (1.f + Ec));
            hreg[r] = (1.f - Ec) * roc;
        }
    }

#pragma unroll
    for (int r = 0; r < 4; ++r)
        hfin[(size_t)(b0 + hrow0 + r) * 128 + jl] = hreg[r];
}

// ---------------------------------------------------------------------------
// post: per row: u=tanh(W1c@h); v=W2@u; res=W0@h+127v; LN; linear; tile 196x
// with float4 stores.   (identical to r11)
// ---------------------------------------------------------------------------
__global__ __launch_bounds__(128) void post_kernel(const char* __restrict__ wsb,
                                                   const float* __restrict__ ln_g,
                                                   const float* __restrict__ ln_b,
                                                   const float* __restrict__ lin_b,
                                                   float* __restrict__ out) {
    const float* hfinal = (const float*)(wsb + OFF_HFIN);
    const float* W1cT   = (const float*)(wsb + OFF_W1CT);
    const float* W2T    = (const float*)(wsb + OFF_W2T);
    const float* W0T    = (const float*)(wsb + OFF_W0T);
    const float* linWT  = (const float*)(wsb + OFF_LINWT);

    __shared__ float sh[128], su[128], sres[128], so_[128], spart[4];
    int b = blockIdx.x, f = threadIdx.x;

    sh[f] = hfinal[(size_t)b * 128 + f];
    __syncthreads();

    float acc = 0.f;
#pragma unroll 4
    for (int k = 0; k < 128; ++k) acc += W1cT[k * 128 + f] * sh[k];
    su[f] = tanhf_fast(acc);
    __syncthreads();

    float v = 0.f, r0 = 0.f;
#pragma unroll 4
    for (int k = 0; k < 128; ++k) {
        v  += W2T[k * 128 + f] * su[k];
        r0 += W0T[k * 128 + f] * sh[k];
    }
    float res = r0 + 127.f * v;

    int lane = f & 63, wid = f >> 6;
    float s = res;
#pragma unroll
    for (int off = 32; off > 0; off >>= 1) s += __shfl_down(s, off);
    if (lane == 0) spart[wid] = s;
    __syncthreads();
    float mu = (spart[0] + spart[1]) * (1.f / 128.f);
    float d = res - mu;
    float s2 = d * d;
#pragma unroll
    for (int off = 32; off > 0; off >>= 1) s2 += __shfl_down(s2, off);
    if (lane == 0) spart[2 + wid] = s2;
    __syncthreads();
    float var = (spart[2] + spart[3]) * (1.f / 128.f);
    float rn = d * rsqrtf(var + 1e-5f) * ln_g[f] + ln_b[f];
    sres[f] = rn;
    __syncthreads();

    float o = lin_b[f];
#pragma unroll 4
    for (int k = 0; k < 128; ++k) o += linWT[k * 128 + f] * sres[k];
    so_[f] = o;
    __syncthreads();

    float4 val = *(const float4*)&so_[(f & 31) << 2];
    float4* op4 = (float4*)(out + (size_t)b * 25088);
#pragma unroll 7
    for (int i = 0; i < 49; ++i) op4[i * 128 + f] = val;
}

// ---------------------------------------------------------------------------
extern "C" void kernel_launch(void* const* d_in, const int* in_sizes, int n_in,
                              void* d_out, int out_size, void* d_ws, size_t ws_size,
                              hipStream_t stream) {
    const float* x      = (const float*)d_in[0];
    const float* conv_w = (const float*)d_in[1];
    const float* conv_b = (const float*)d_in[2];
    const float* w_ih   = (const float*)d_in[3];
    const float* w_hh   = (const float*)d_in[4];
    const float* b_ih   = (const float*)d_in[5];
    const float* b_hh   = (const float*)d_in[6];
    const float* W1     = (const float*)d_in[7];
    const float* W2     = (const float*)d_in[8];
    const float* W0     = (const float*)d_in[9];
    const float* ln_g   = (const float*)d_in[10];
    const float* ln_b   = (const float*)d_in[11];
    const float* lin_w  = (const float*)d_in[12];
    const float* lin_b  = (const float*)d_in[13];
    char* wsb  = (char*)d_ws;
    float* out = (float*)d_out;

    prep_conv_kernel<<<dim3(1345), dim3(512), 0, stream>>>(w_ih, w_hh, b_ih, b_hh,
                                                           W1, W2, W0, lin_w,
                                                           x, conv_w, conv_b, wsb);
    lstm_mfma<<<dim3(64), dim3(512), 0, stream>>>(wsb, wsb);
    post_kernel<<<dim3(1024), dim3(128), 0, stream>>>(wsb, ln_g, ln_b, lin_b, out);
}